// Round 12
// baseline (460.463 us; speedup 1.0000x reference)
//
#include <hip/hip_runtime.h>

#define DIM 128
#define EPS 1e-5f
#define SCAN_TILE 2048  // 256 threads x 8 elements

typedef short s16x8 __attribute__((ext_vector_type(8)));
typedef unsigned short u16x8 __attribute__((ext_vector_type(8)));
typedef float f32x4 __attribute__((ext_vector_type(4)));

__device__ __forceinline__ int lower_bound_i(const int* __restrict__ a, int n, int key) {
  int lo = 0, hi = n;
  while (lo < hi) {
    int mid = (lo + hi) >> 1;
    if (a[mid] < key) lo = mid + 1; else hi = mid;
  }
  return lo;
}

__device__ __forceinline__ unsigned rne_bf16(float f) {
  unsigned u = __builtin_bit_cast(unsigned, f);
  return (u + 0x7fffu + ((u >> 16) & 1u)) >> 16;
}
__device__ __forceinline__ float bf16_hi_to_f32(unsigned h) {
  return __builtin_bit_cast(float, h << 16);
}

// --- prep: zero the zero-region AND split/transpose W (both layers) --------
__global__ __launch_bounds__(256) void prep_kernel(float4* __restrict__ z, int n4,
    const float* __restrict__ W_l, const float* __restrict__ W_r,
    unsigned short* __restrict__ Wth, unsigned short* __restrict__ Wtl, int nW) {
  int i = blockIdx.x * 256 + threadIdx.x;
  if (i < n4) z[i] = make_float4(0.f, 0.f, 0.f, 0.f);
  if (i < nW) {  // i = l*DIM*256 + c*256 + k
    int l = i / (DIM * 256);
    int rem = i - l * DIM * 256;
    int c = rem >> 8, k = rem & 255;
    const float* Wl = W_l + (size_t)l * DIM * DIM;
    const float* Wr = W_r + (size_t)l * DIM * DIM;
    float v = (k < DIM) ? Wl[(size_t)k * DIM + c] : Wr[(size_t)(k - DIM) * DIM + c];
    unsigned h = rne_bf16(v);
    float r = v - bf16_hi_to_f32(h);
    Wth[i] = (unsigned short)h;
    Wtl[i] = (unsigned short)rne_bf16(r);
  }
}

// --- histogram + bf16 shadow of layer-1 activations (merged) ---------------
__global__ __launch_bounds__(256) void hist_cvt_kernel(const int* __restrict__ dst,
    int* __restrict__ cnt, const float* __restrict__ x,
    unsigned short* __restrict__ xh, int nE, int total8) {
  int i = blockIdx.x * 256 + threadIdx.x;
  if (i < nE) atomicAdd(&cnt[dst[i]], 1);
  if (i < total8) {
    float4 a = reinterpret_cast<const float4*>(x)[i * 2];
    float4 b = reinterpret_cast<const float4*>(x)[i * 2 + 1];
    u16x8 o;
    o[0] = (unsigned short)rne_bf16(a.x); o[1] = (unsigned short)rne_bf16(a.y);
    o[2] = (unsigned short)rne_bf16(a.z); o[3] = (unsigned short)rne_bf16(a.w);
    o[4] = (unsigned short)rne_bf16(b.x); o[5] = (unsigned short)rne_bf16(b.y);
    o[6] = (unsigned short)rne_bf16(b.z); o[7] = (unsigned short)rne_bf16(b.w);
    reinterpret_cast<u16x8*>(xh)[i] = o;
  }
}

// --- 2-phase scan (scan2 folded into scan3) --------------------------------
__global__ __launch_bounds__(256) void scan1_kernel(const int* __restrict__ cnt,
                                                    int* __restrict__ bsum, int nN) {
  __shared__ int s[256];
  int t = threadIdx.x;
  int base = blockIdx.x * SCAN_TILE + t * 8;
  int sum = 0;
#pragma unroll
  for (int j = 0; j < 8; ++j) {
    int i = base + j;
    if (i < nN) sum += cnt[i];
  }
  s[t] = sum;
  __syncthreads();
  for (int off = 128; off > 0; off >>= 1) {
    if (t < off) s[t] += s[t + off];
    __syncthreads();
  }
  if (t == 0) bsum[blockIdx.x] = s[0];
}

// Each block locally prefix-scans the (small) bsum array, then does its tile.
__global__ __launch_bounds__(256) void scan3_kernel(const int* __restrict__ cnt,
                                                    const int* __restrict__ bsum,
                                                    int* __restrict__ rowptr,
                                                    int nB, int nN) {
  __shared__ int s[256];
  __shared__ int s_base;
  int t = threadIdx.x;
  if (t == 0) {
    int run = 0;
    for (int b = 0; b < nB; ++b) {
      if (b == blockIdx.x) { s_base = run; }
      run += bsum[b];
    }
    if (blockIdx.x == 0) rowptr[nN] = run;
  }
  int base = blockIdx.x * SCAN_TILE + t * 8;
  int v[8];
  int tsum = 0;
#pragma unroll
  for (int j = 0; j < 8; ++j) {
    int i = base + j;
    v[j] = (i < nN) ? cnt[i] : 0;
    tsum += v[j];
  }
  s[t] = tsum;
  __syncthreads();
  for (int off = 1; off < 256; off <<= 1) {
    int u = (t >= off) ? s[t - off] : 0;
    __syncthreads();
    s[t] += u;
    __syncthreads();
  }
  int run = s_base + ((t > 0) ? s[t - 1] : 0);
#pragma unroll
  for (int j = 0; j < 8; ++j) {
    int i = base + j;
    if (i < nN) rowptr[i] = run;
    run += v[j];
  }
}

__global__ __launch_bounds__(256) void fill_kernel(const int* __restrict__ src,
    const int* __restrict__ dst, const int* __restrict__ rowptr,
    int* __restrict__ cursor, int* __restrict__ eidx, int nE) {
  int e = blockIdx.x * 256 + threadIdx.x;
  if (e < nE) {
    int d = dst[e];
    int p = atomicAdd(&cursor[d], 1);
    eidx[rowptr[d] + p] = src[e];
  }
}

// --- mean-aggregate via gather: 16 threads per dst node, bf16 in/out -------
__global__ __launch_bounds__(256) void gather_kernel(const unsigned short* __restrict__ xh,
    const int* __restrict__ rowptr, const int* __restrict__ eidx,
    unsigned short* __restrict__ aggh, int nN) {
  int grp = (blockIdx.x * 256 + threadIdx.x) >> 4;
  int j = threadIdx.x & 15;  // 8 cols per lane
  if (grp >= nN) return;
  int lo = rowptr[grp], hi = rowptr[grp + 1];
  float acc[8] = {0.f, 0.f, 0.f, 0.f, 0.f, 0.f, 0.f, 0.f};
  int i = lo;
  for (; i + 1 < hi; i += 2) {
    int s0 = eidx[i], s1 = eidx[i + 1];
    u16x8 v0 = *reinterpret_cast<const u16x8*>(xh + (size_t)s0 * DIM + j * 8);
    u16x8 v1 = *reinterpret_cast<const u16x8*>(xh + (size_t)s1 * DIM + j * 8);
#pragma unroll
    for (int q = 0; q < 8; ++q) {
      acc[q] += bf16_hi_to_f32(v0[q]);
      acc[q] += bf16_hi_to_f32(v1[q]);
    }
  }
  if (i < hi) {
    int s0 = eidx[i];
    u16x8 v0 = *reinterpret_cast<const u16x8*>(xh + (size_t)s0 * DIM + j * 8);
#pragma unroll
    for (int q = 0; q < 8; ++q) acc[q] += bf16_hi_to_f32(v0[q]);
  }
  float invd = 1.0f / fmaxf((float)(hi - lo), 1.0f);
  u16x8 o;
#pragma unroll
  for (int q = 0; q < 8; ++q) o[q] = (unsigned short)rne_bf16(acc[q] * invd);
  *reinterpret_cast<u16x8*>(aggh + (size_t)grp * DIM + j * 8) = o;
}

// --- fused dual-GEMM (bf16 A x split-W MFMA) + BN-stats epilogue -----------
__global__ __launch_bounds__(256) void gemm_mfma_kernel(
    const unsigned short* __restrict__ A0h, const unsigned short* __restrict__ A1h,
    const unsigned short* __restrict__ Wth, const unsigned short* __restrict__ Wtl,
    const float* __restrict__ bias, unsigned short* __restrict__ h,
    float* __restrict__ sums, int nN) {
  __shared__ unsigned short Wh_lds[DIM * 128];  // 32KB, [c][k] swizzled
  __shared__ unsigned short Wl_lds[DIM * 128];  // 32KB
  __shared__ float s_sum[DIM];
  __shared__ float s_sq[DIM];
  const int tid = threadIdx.x;
  const int lane = tid & 63;
  const int wave = tid >> 6;
  const int rbase = blockIdx.x * 128 + wave * 32;
  const int lrow = lane & 15;
  const int koff = (lane >> 4) * 8;

  f32x4 acc[2][8];
#pragma unroll
  for (int rt = 0; rt < 2; ++rt)
#pragma unroll
    for (int ct = 0; ct < 8; ++ct)
      acc[rt][ct] = (f32x4){0.f, 0.f, 0.f, 0.f};

  int r0 = rbase + lrow;      if (r0 > nN - 1) r0 = nN - 1;
  int r1 = rbase + 16 + lrow; if (r1 > nN - 1) r1 = nN - 1;

#pragma unroll
  for (int s = 0; s < 2; ++s) {
    __syncthreads();
#pragma unroll
    for (int i = 0; i < 8; ++i) {
      int idx = i * 256 + tid;   // 0..2047
      int c = idx >> 4;
      int kc = idx & 15;
      int lb = c * 256 + ((kc * 16) ^ ((c & 7) << 4));
      float4 hv = *reinterpret_cast<const float4*>(Wth + (size_t)c * 256 + s * 128 + kc * 8);
      float4 lv = *reinterpret_cast<const float4*>(Wtl + (size_t)c * 256 + s * 128 + kc * 8);
      *reinterpret_cast<float4*>(reinterpret_cast<char*>(Wh_lds) + lb) = hv;
      *reinterpret_cast<float4*>(reinterpret_cast<char*>(Wl_lds) + lb) = lv;
    }
    __syncthreads();

    const unsigned short* A = s ? A1h : A0h;
#pragma unroll
    for (int ks = 0; ks < 4; ++ks) {
      int ka = ks * 32 + koff;
      s16x8 a0 = *reinterpret_cast<const s16x8*>(A + (size_t)r0 * DIM + ka);
      s16x8 a1 = *reinterpret_cast<const s16x8*>(A + (size_t)r1 * DIM + ka);
#pragma unroll
      for (int ct = 0; ct < 8; ++ct) {
        int c = ct * 16 + lrow;
        int lb = c * 256 + ((ka * 2) ^ ((c & 7) << 4));
        s16x8 wh = *reinterpret_cast<const s16x8*>(reinterpret_cast<const char*>(Wh_lds) + lb);
        s16x8 wl = *reinterpret_cast<const s16x8*>(reinterpret_cast<const char*>(Wl_lds) + lb);
        acc[0][ct] = __builtin_amdgcn_mfma_f32_16x16x32_bf16(a0, wh, acc[0][ct], 0, 0, 0);
        acc[0][ct] = __builtin_amdgcn_mfma_f32_16x16x32_bf16(a0, wl, acc[0][ct], 0, 0, 0);
        acc[1][ct] = __builtin_amdgcn_mfma_f32_16x16x32_bf16(a1, wh, acc[1][ct], 0, 0, 0);
        acc[1][ct] = __builtin_amdgcn_mfma_f32_16x16x32_bf16(a1, wl, acc[1][ct], 0, 0, 0);
      }
    }
  }

  // epilogue: store h (bf16) and accumulate BN stats from fp32 values
  if (tid < DIM) { s_sum[tid] = 0.f; s_sq[tid] = 0.f; }
  __syncthreads();
  float csum[8], csq[8];
#pragma unroll
  for (int ct = 0; ct < 8; ++ct) { csum[ct] = 0.f; csq[ct] = 0.f; }
#pragma unroll
  for (int ct = 0; ct < 8; ++ct) {
    int c = ct * 16 + lrow;
    float b = bias[c];
#pragma unroll
    for (int rt = 0; rt < 2; ++rt) {
      int rr = rbase + rt * 16 + (lane >> 4) * 4;
#pragma unroll
      for (int j = 0; j < 4; ++j) {
        int row = rr + j;
        if (row < nN) {
          float v = acc[rt][ct][j] + b;
          h[(size_t)row * DIM + c] = (unsigned short)rne_bf16(v);
          csum[ct] += v;
          csq[ct] += v * v;
        }
      }
    }
  }
#pragma unroll
  for (int ct = 0; ct < 8; ++ct) {
    csum[ct] += __shfl_xor(csum[ct], 16);
    csum[ct] += __shfl_xor(csum[ct], 32);
    csq[ct]  += __shfl_xor(csq[ct], 16);
    csq[ct]  += __shfl_xor(csq[ct], 32);
  }
  if (lane < 16) {
#pragma unroll
    for (int ct = 0; ct < 8; ++ct) {
      atomicAdd(&s_sum[ct * 16 + lane], csum[ct]);
      atomicAdd(&s_sq[ct * 16 + lane], csq[ct]);
    }
  }
  __syncthreads();
  if (tid < DIM) {
    atomicAdd(&sums[tid], s_sum[tid]);
    atomicAdd(&sums[DIM + tid], s_sq[tid]);
  }
}

// BN+ReLU: bf16 h in, bf16 activations out (8 elems/thread).
__global__ __launch_bounds__(256) void bn_relu_kernel(const unsigned short* __restrict__ h,
    const float* __restrict__ sums, const float* __restrict__ gamma,
    const float* __restrict__ beta, unsigned short* __restrict__ xhout, int nN) {
  int idx = blockIdx.x * 256 + threadIdx.x;
  int total = nN * (DIM / 8);
  if (idx >= total) return;
  int c = (idx & 15) * 8;
  float invN = 1.0f / (float)nN;
  u16x8 hv = reinterpret_cast<const u16x8*>(h)[idx];
  u16x8 oh;
#pragma unroll
  for (int j = 0; j < 8; ++j) {
    float mu = sums[c + j] * invN;
    float var = sums[DIM + c + j] * invN - mu * mu;
    float sc = gamma[c + j] * rsqrtf(var + EPS);
    float sh = beta[c + j] - mu * sc;
    float v = fmaxf(bf16_hi_to_f32(hv[j]) * sc + sh, 0.0f);
    oh[j] = (unsigned short)rne_bf16(v);
  }
  reinterpret_cast<u16x8*>(xhout)[idx] = oh;
}

// --- fused final BN+ReLU + segmented mean-pool + last-block division --------
#define POOL_ROWS 32
__global__ __launch_bounds__(256) void pool_fused_kernel(const unsigned short* __restrict__ h,
    const float* __restrict__ sums, const float* __restrict__ gamma,
    const float* __restrict__ beta, const int* __restrict__ batch,
    float* __restrict__ outsum, float* __restrict__ out, int* __restrict__ done,
    int nN, int nG) {
  int c = threadIdx.x & 127;
  int rp = threadIdx.x >> 7;
  int r0 = blockIdx.x * POOL_ROWS;
  float invN = 1.0f / (float)nN;
  float mu = sums[c] * invN;
  float var = sums[DIM + c] * invN - mu * mu;
  float sc = gamma[c] * rsqrtf(var + EPS);
  float sh = beta[c] - mu * sc;
  int rend = min(r0 + POOL_ROWS, nN);
  float acc = 0.f;
  int cur = -1;
  for (int r = r0 + rp; r < rend; r += 2) {
    int g = batch[r];
    float v = fmaxf(bf16_hi_to_f32(h[(size_t)r * DIM + c]) * sc + sh, 0.0f);
    if (g != cur) {
      if (cur >= 0) atomicAdd(&outsum[(size_t)cur * DIM + c], acc);
      cur = g; acc = 0.f;
    }
    acc += v;
  }
  if (cur >= 0) atomicAdd(&outsum[(size_t)cur * DIM + c], acc);

  // last-block-done: the final block divides by counts and writes out.
  __threadfence();
  __syncthreads();
  __shared__ int s_last;
  if (threadIdx.x == 0) s_last = (atomicAdd(done, 1) == (int)gridDim.x - 1);
  __syncthreads();
  if (s_last) {
    __threadfence();  // acquire: see all blocks' outsum atomics
    for (int idx = threadIdx.x; idx < nG * DIM; idx += 256) {
      int g = idx >> 7;
      int lo = lower_bound_i(batch, nN, g);
      int hi = lower_bound_i(batch, nN, g + 1);
      float cnt = fmaxf((float)(hi - lo), 1.0f);
      out[idx] = outsum[idx] / cnt;
    }
  }
}

extern "C" void kernel_launch(void* const* d_in, const int* in_sizes, int n_in,
                              void* d_out, int out_size, void* d_ws, size_t ws_size,
                              hipStream_t stream) {
  const float* x     = (const float*)d_in[0];
  const int*   ei    = (const int*)d_in[1];
  const int*   batch = (const int*)d_in[2];
  const float* W_l   = (const float*)d_in[3];
  const float* b_l   = (const float*)d_in[4];
  const float* W_r   = (const float*)d_in[5];
  const float* gamma = (const float*)d_in[6];
  const float* beta  = (const float*)d_in[7];
  float* out = (float*)d_out;

  const int N = in_sizes[2];
  const int E = in_sizes[1] / 2;
  const int G = out_size / DIM;
  const int L = in_sizes[3] / (DIM * DIM);

  const int* src  = ei;
  const int* dstE = ei + E;

  const int nB = (N + SCAN_TILE - 1) / SCAN_TILE;

  // workspace layout (zeroed region contiguous: cnt|cursor|sums(L)|outsum|done)
  char* wsb = (char*)d_ws;
  unsigned short* h    = (unsigned short*)wsb; wsb += (size_t)N * DIM * sizeof(unsigned short);
  unsigned short* xh   = (unsigned short*)wsb; wsb += (size_t)N * DIM * sizeof(unsigned short);
  unsigned short* aggh = (unsigned short*)wsb; wsb += (size_t)N * DIM * sizeof(unsigned short);
  unsigned short* Wth  = (unsigned short*)wsb; wsb += (size_t)L * DIM * 256 * sizeof(unsigned short);
  unsigned short* Wtl  = (unsigned short*)wsb; wsb += (size_t)L * DIM * 256 * sizeof(unsigned short);
  char* zbase = wsb;
  int* cnt      = (int*)wsb;    wsb += (size_t)N * sizeof(int);
  int* cursor   = (int*)wsb;    wsb += (size_t)N * sizeof(int);
  float* sums   = (float*)wsb;  wsb += (size_t)L * 2 * DIM * sizeof(float);
  float* outsum = (float*)wsb;  wsb += (size_t)G * DIM * sizeof(float);
  int* done     = (int*)wsb;    wsb += 4 * sizeof(int);
  int zbytes = (int)((char*)wsb - zbase);
  int* rowptr = (int*)wsb;      wsb += (size_t)(N + 1) * sizeof(int);
  int* bsum   = (int*)wsb;      wsb += (size_t)nB * sizeof(int);
  int* eidx   = (int*)wsb;      wsb += (size_t)E * sizeof(int);

  // 1. zero region + W prep (one node)
  int n4 = zbytes / 16;
  int nW = L * DIM * 256;
  int prep_n = max(n4, nW);
  prep_kernel<<<(prep_n + 255) / 256, 256, 0, stream>>>((float4*)zbase, n4,
      W_l, W_r, Wth, Wtl, nW);
  // 2. histogram + bf16 shadow of x
  int total8 = N * (DIM / 8);
  int histcvt_n = max(E, total8);
  hist_cvt_kernel<<<(histcvt_n + 255) / 256, 256, 0, stream>>>(dstE, cnt, x, xh, E, total8);
  // 3-4. scan (scan2 folded into scan3)
  scan1_kernel<<<nB, 256, 0, stream>>>(cnt, bsum, N);
  scan3_kernel<<<nB, 256, 0, stream>>>(cnt, bsum, rowptr, nB, N);
  // 5. CSR fill
  fill_kernel<<<(E + 255) / 256, 256, 0, stream>>>(src, dstE, rowptr, cursor, eidx, E);

  for (int l = 0; l < L; ++l) {
    gather_kernel<<<(N * 16 + 255) / 256, 256, 0, stream>>>(xh, rowptr, eidx, aggh, N);
    gemm_mfma_kernel<<<(N + 127) / 128, 256, 0, stream>>>(aggh, xh,
        Wth + (size_t)l * DIM * 256, Wtl + (size_t)l * DIM * 256,
        b_l + (size_t)l * DIM, h, sums + (size_t)l * 2 * DIM, N);
    if (l < L - 1) {
      bn_relu_kernel<<<(N * (DIM / 8) + 255) / 256, 256, 0, stream>>>(
          h, sums + (size_t)l * 2 * DIM, gamma + (size_t)l * DIM,
          beta + (size_t)l * DIM, xh, N);
    } else {
      pool_fused_kernel<<<(N + POOL_ROWS - 1) / POOL_ROWS, 256, 0, stream>>>(
          h, sums + (size_t)l * 2 * DIM, gamma + (size_t)l * DIM,
          beta + (size_t)l * DIM, batch, outsum, out, done, N, G);
    }
  }
}

// Round 13
// 308.435 us; speedup vs baseline: 1.4929x; 1.4929x over previous
//
#include <hip/hip_runtime.h>

#define DIM 128
#define EPS 1e-5f
#define SCAN_TILE 2048  // 256 threads x 8 elements

typedef short s16x8 __attribute__((ext_vector_type(8)));
typedef unsigned short u16x8 __attribute__((ext_vector_type(8)));
typedef float f32x4 __attribute__((ext_vector_type(4)));

__device__ __forceinline__ int lower_bound_i(const int* __restrict__ a, int n, int key) {
  int lo = 0, hi = n;
  while (lo < hi) {
    int mid = (lo + hi) >> 1;
    if (a[mid] < key) lo = mid + 1; else hi = mid;
  }
  return lo;
}

__device__ __forceinline__ unsigned rne_bf16(float f) {
  unsigned u = __builtin_bit_cast(unsigned, f);
  return (u + 0x7fffu + ((u >> 16) & 1u)) >> 16;
}
__device__ __forceinline__ float bf16_hi_to_f32(unsigned h) {
  return __builtin_bit_cast(float, h << 16);
}

// --- prep: zero the zero-region AND split/transpose W (both layers) --------
__global__ __launch_bounds__(256) void prep_kernel(float4* __restrict__ z, int n4,
    const float* __restrict__ W_l, const float* __restrict__ W_r,
    unsigned short* __restrict__ Wth, unsigned short* __restrict__ Wtl, int nW) {
  int i = blockIdx.x * 256 + threadIdx.x;
  if (i < n4) z[i] = make_float4(0.f, 0.f, 0.f, 0.f);
  if (i < nW) {  // i = l*DIM*256 + c*256 + k
    int l = i / (DIM * 256);
    int rem = i - l * DIM * 256;
    int c = rem >> 8, k = rem & 255;
    const float* Wl = W_l + (size_t)l * DIM * DIM;
    const float* Wr = W_r + (size_t)l * DIM * DIM;
    float v = (k < DIM) ? Wl[(size_t)k * DIM + c] : Wr[(size_t)(k - DIM) * DIM + c];
    unsigned h = rne_bf16(v);
    float r = v - bf16_hi_to_f32(h);
    Wth[i] = (unsigned short)h;
    Wtl[i] = (unsigned short)rne_bf16(r);
  }
}

// --- histogram + bf16 shadow of layer-1 activations (merged) ---------------
__global__ __launch_bounds__(256) void hist_cvt_kernel(const int* __restrict__ dst,
    int* __restrict__ cnt, const float* __restrict__ x,
    unsigned short* __restrict__ xh, int nE, int total8) {
  int i = blockIdx.x * 256 + threadIdx.x;
  if (i < nE) atomicAdd(&cnt[dst[i]], 1);
  if (i < total8) {
    float4 a = reinterpret_cast<const float4*>(x)[i * 2];
    float4 b = reinterpret_cast<const float4*>(x)[i * 2 + 1];
    u16x8 o;
    o[0] = (unsigned short)rne_bf16(a.x); o[1] = (unsigned short)rne_bf16(a.y);
    o[2] = (unsigned short)rne_bf16(a.z); o[3] = (unsigned short)rne_bf16(a.w);
    o[4] = (unsigned short)rne_bf16(b.x); o[5] = (unsigned short)rne_bf16(b.y);
    o[6] = (unsigned short)rne_bf16(b.z); o[7] = (unsigned short)rne_bf16(b.w);
    reinterpret_cast<u16x8*>(xh)[i] = o;
  }
}

// --- 2-phase scan (scan2 folded into scan3) --------------------------------
__global__ __launch_bounds__(256) void scan1_kernel(const int* __restrict__ cnt,
                                                    int* __restrict__ bsum, int nN) {
  __shared__ int s[256];
  int t = threadIdx.x;
  int base = blockIdx.x * SCAN_TILE + t * 8;
  int sum = 0;
#pragma unroll
  for (int j = 0; j < 8; ++j) {
    int i = base + j;
    if (i < nN) sum += cnt[i];
  }
  s[t] = sum;
  __syncthreads();
  for (int off = 128; off > 0; off >>= 1) {
    if (t < off) s[t] += s[t + off];
    __syncthreads();
  }
  if (t == 0) bsum[blockIdx.x] = s[0];
}

// Each block locally prefix-scans the (small) bsum array, then does its tile.
__global__ __launch_bounds__(256) void scan3_kernel(const int* __restrict__ cnt,
                                                    const int* __restrict__ bsum,
                                                    int* __restrict__ rowptr,
                                                    int nB, int nN) {
  __shared__ int s[256];
  __shared__ int s_base;
  int t = threadIdx.x;
  if (t == 0) {
    int run = 0;
    for (int b = 0; b < nB; ++b) {
      if (b == blockIdx.x) { s_base = run; }
      run += bsum[b];
    }
    if (blockIdx.x == 0) rowptr[nN] = run;
  }
  int base = blockIdx.x * SCAN_TILE + t * 8;
  int v[8];
  int tsum = 0;
#pragma unroll
  for (int j = 0; j < 8; ++j) {
    int i = base + j;
    v[j] = (i < nN) ? cnt[i] : 0;
    tsum += v[j];
  }
  s[t] = tsum;
  __syncthreads();
  for (int off = 1; off < 256; off <<= 1) {
    int u = (t >= off) ? s[t - off] : 0;
    __syncthreads();
    s[t] += u;
    __syncthreads();
  }
  int run = s_base + ((t > 0) ? s[t - 1] : 0);
#pragma unroll
  for (int j = 0; j < 8; ++j) {
    int i = base + j;
    if (i < nN) rowptr[i] = run;
    run += v[j];
  }
}

__global__ __launch_bounds__(256) void fill_kernel(const int* __restrict__ src,
    const int* __restrict__ dst, const int* __restrict__ rowptr,
    int* __restrict__ cursor, int* __restrict__ eidx, int nE) {
  int e = blockIdx.x * 256 + threadIdx.x;
  if (e < nE) {
    int d = dst[e];
    int p = atomicAdd(&cursor[d], 1);
    eidx[rowptr[d] + p] = src[e];
  }
}

// --- mean-aggregate via gather: 16 threads per dst node, bf16 in/out -------
__global__ __launch_bounds__(256) void gather_kernel(const unsigned short* __restrict__ xh,
    const int* __restrict__ rowptr, const int* __restrict__ eidx,
    unsigned short* __restrict__ aggh, int nN) {
  int grp = (blockIdx.x * 256 + threadIdx.x) >> 4;
  int j = threadIdx.x & 15;  // 8 cols per lane
  if (grp >= nN) return;
  int lo = rowptr[grp], hi = rowptr[grp + 1];
  float acc[8] = {0.f, 0.f, 0.f, 0.f, 0.f, 0.f, 0.f, 0.f};
  int i = lo;
  for (; i + 1 < hi; i += 2) {
    int s0 = eidx[i], s1 = eidx[i + 1];
    u16x8 v0 = *reinterpret_cast<const u16x8*>(xh + (size_t)s0 * DIM + j * 8);
    u16x8 v1 = *reinterpret_cast<const u16x8*>(xh + (size_t)s1 * DIM + j * 8);
#pragma unroll
    for (int q = 0; q < 8; ++q) {
      acc[q] += bf16_hi_to_f32(v0[q]);
      acc[q] += bf16_hi_to_f32(v1[q]);
    }
  }
  if (i < hi) {
    int s0 = eidx[i];
    u16x8 v0 = *reinterpret_cast<const u16x8*>(xh + (size_t)s0 * DIM + j * 8);
#pragma unroll
    for (int q = 0; q < 8; ++q) acc[q] += bf16_hi_to_f32(v0[q]);
  }
  float invd = 1.0f / fmaxf((float)(hi - lo), 1.0f);
  u16x8 o;
#pragma unroll
  for (int q = 0; q < 8; ++q) o[q] = (unsigned short)rne_bf16(acc[q] * invd);
  *reinterpret_cast<u16x8*>(aggh + (size_t)grp * DIM + j * 8) = o;
}

// --- fused dual-GEMM (bf16 A x split-W MFMA) + BN-stats epilogue -----------
__global__ __launch_bounds__(256) void gemm_mfma_kernel(
    const unsigned short* __restrict__ A0h, const unsigned short* __restrict__ A1h,
    const unsigned short* __restrict__ Wth, const unsigned short* __restrict__ Wtl,
    const float* __restrict__ bias, unsigned short* __restrict__ h,
    float* __restrict__ sums, int nN) {
  __shared__ unsigned short Wh_lds[DIM * 128];  // 32KB, [c][k] swizzled
  __shared__ unsigned short Wl_lds[DIM * 128];  // 32KB
  __shared__ float s_sum[DIM];
  __shared__ float s_sq[DIM];
  const int tid = threadIdx.x;
  const int lane = tid & 63;
  const int wave = tid >> 6;
  const int rbase = blockIdx.x * 128 + wave * 32;
  const int lrow = lane & 15;
  const int koff = (lane >> 4) * 8;

  f32x4 acc[2][8];
#pragma unroll
  for (int rt = 0; rt < 2; ++rt)
#pragma unroll
    for (int ct = 0; ct < 8; ++ct)
      acc[rt][ct] = (f32x4){0.f, 0.f, 0.f, 0.f};

  int r0 = rbase + lrow;      if (r0 > nN - 1) r0 = nN - 1;
  int r1 = rbase + 16 + lrow; if (r1 > nN - 1) r1 = nN - 1;

#pragma unroll
  for (int s = 0; s < 2; ++s) {
    __syncthreads();
#pragma unroll
    for (int i = 0; i < 8; ++i) {
      int idx = i * 256 + tid;   // 0..2047
      int c = idx >> 4;
      int kc = idx & 15;
      int lb = c * 256 + ((kc * 16) ^ ((c & 7) << 4));
      float4 hv = *reinterpret_cast<const float4*>(Wth + (size_t)c * 256 + s * 128 + kc * 8);
      float4 lv = *reinterpret_cast<const float4*>(Wtl + (size_t)c * 256 + s * 128 + kc * 8);
      *reinterpret_cast<float4*>(reinterpret_cast<char*>(Wh_lds) + lb) = hv;
      *reinterpret_cast<float4*>(reinterpret_cast<char*>(Wl_lds) + lb) = lv;
    }
    __syncthreads();

    const unsigned short* A = s ? A1h : A0h;
#pragma unroll
    for (int ks = 0; ks < 4; ++ks) {
      int ka = ks * 32 + koff;
      s16x8 a0 = *reinterpret_cast<const s16x8*>(A + (size_t)r0 * DIM + ka);
      s16x8 a1 = *reinterpret_cast<const s16x8*>(A + (size_t)r1 * DIM + ka);
#pragma unroll
      for (int ct = 0; ct < 8; ++ct) {
        int c = ct * 16 + lrow;
        int lb = c * 256 + ((ka * 2) ^ ((c & 7) << 4));
        s16x8 wh = *reinterpret_cast<const s16x8*>(reinterpret_cast<const char*>(Wh_lds) + lb);
        s16x8 wl = *reinterpret_cast<const s16x8*>(reinterpret_cast<const char*>(Wl_lds) + lb);
        acc[0][ct] = __builtin_amdgcn_mfma_f32_16x16x32_bf16(a0, wh, acc[0][ct], 0, 0, 0);
        acc[0][ct] = __builtin_amdgcn_mfma_f32_16x16x32_bf16(a0, wl, acc[0][ct], 0, 0, 0);
        acc[1][ct] = __builtin_amdgcn_mfma_f32_16x16x32_bf16(a1, wh, acc[1][ct], 0, 0, 0);
        acc[1][ct] = __builtin_amdgcn_mfma_f32_16x16x32_bf16(a1, wl, acc[1][ct], 0, 0, 0);
      }
    }
  }

  // epilogue: store h (bf16) and accumulate BN stats from fp32 values
  if (tid < DIM) { s_sum[tid] = 0.f; s_sq[tid] = 0.f; }
  __syncthreads();
  float csum[8], csq[8];
#pragma unroll
  for (int ct = 0; ct < 8; ++ct) { csum[ct] = 0.f; csq[ct] = 0.f; }
#pragma unroll
  for (int ct = 0; ct < 8; ++ct) {
    int c = ct * 16 + lrow;
    float b = bias[c];
#pragma unroll
    for (int rt = 0; rt < 2; ++rt) {
      int rr = rbase + rt * 16 + (lane >> 4) * 4;
#pragma unroll
      for (int j = 0; j < 4; ++j) {
        int row = rr + j;
        if (row < nN) {
          float v = acc[rt][ct][j] + b;
          h[(size_t)row * DIM + c] = (unsigned short)rne_bf16(v);
          csum[ct] += v;
          csq[ct] += v * v;
        }
      }
    }
  }
#pragma unroll
  for (int ct = 0; ct < 8; ++ct) {
    csum[ct] += __shfl_xor(csum[ct], 16);
    csum[ct] += __shfl_xor(csum[ct], 32);
    csq[ct]  += __shfl_xor(csq[ct], 16);
    csq[ct]  += __shfl_xor(csq[ct], 32);
  }
  if (lane < 16) {
#pragma unroll
    for (int ct = 0; ct < 8; ++ct) {
      atomicAdd(&s_sum[ct * 16 + lane], csum[ct]);
      atomicAdd(&s_sq[ct * 16 + lane], csq[ct]);
    }
  }
  __syncthreads();
  if (tid < DIM) {
    atomicAdd(&sums[tid], s_sum[tid]);
    atomicAdd(&sums[DIM + tid], s_sq[tid]);
  }
}

// BN+ReLU: bf16 h in, bf16 activations out (8 elems/thread).
__global__ __launch_bounds__(256) void bn_relu_kernel(const unsigned short* __restrict__ h,
    const float* __restrict__ sums, const float* __restrict__ gamma,
    const float* __restrict__ beta, unsigned short* __restrict__ xhout, int nN) {
  int idx = blockIdx.x * 256 + threadIdx.x;
  int total = nN * (DIM / 8);
  if (idx >= total) return;
  int c = (idx & 15) * 8;
  float invN = 1.0f / (float)nN;
  u16x8 hv = reinterpret_cast<const u16x8*>(h)[idx];
  u16x8 oh;
#pragma unroll
  for (int j = 0; j < 8; ++j) {
    float mu = sums[c + j] * invN;
    float var = sums[DIM + c + j] * invN - mu * mu;
    float sc = gamma[c + j] * rsqrtf(var + EPS);
    float sh = beta[c + j] - mu * sc;
    float v = fmaxf(bf16_hi_to_f32(hv[j]) * sc + sh, 0.0f);
    oh[j] = (unsigned short)rne_bf16(v);
  }
  reinterpret_cast<u16x8*>(xhout)[idx] = oh;
}

// --- fused final BN+ReLU + segmented mean-pool + last-block division --------
// Last block caches per-graph 1/cnt in LDS (parallel binary searches, one per
// thread g < nG) before the grid-stride division — avoids the serial
// 1024-deep dependent-load chain that cost 266us in R12.
#define POOL_ROWS 32
__global__ __launch_bounds__(256) void pool_fused_kernel(const unsigned short* __restrict__ h,
    const float* __restrict__ sums, const float* __restrict__ gamma,
    const float* __restrict__ beta, const int* __restrict__ batch,
    float* __restrict__ outsum, float* __restrict__ out, int* __restrict__ done,
    int nN, int nG) {
  int c = threadIdx.x & 127;
  int rp = threadIdx.x >> 7;
  int r0 = blockIdx.x * POOL_ROWS;
  float invN = 1.0f / (float)nN;
  float mu = sums[c] * invN;
  float var = sums[DIM + c] * invN - mu * mu;
  float sc = gamma[c] * rsqrtf(var + EPS);
  float sh = beta[c] - mu * sc;
  int rend = min(r0 + POOL_ROWS, nN);
  float acc = 0.f;
  int cur = -1;
  for (int r = r0 + rp; r < rend; r += 2) {
    int g = batch[r];
    float v = fmaxf(bf16_hi_to_f32(h[(size_t)r * DIM + c]) * sc + sh, 0.0f);
    if (g != cur) {
      if (cur >= 0) atomicAdd(&outsum[(size_t)cur * DIM + c], acc);
      cur = g; acc = 0.f;
    }
    acc += v;
  }
  if (cur >= 0) atomicAdd(&outsum[(size_t)cur * DIM + c], acc);

  // last-block-done: the final block divides by counts and writes out.
  __threadfence();
  __syncthreads();
  __shared__ int s_last;
  __shared__ float s_inv[256];
  if (threadIdx.x == 0) s_last = (atomicAdd(done, 1) == (int)gridDim.x - 1);
  __syncthreads();
  if (s_last) {
    __threadfence();  // acquire: see all blocks' outsum atomics
    if (threadIdx.x < nG) {
      int g = threadIdx.x;
      int lo = lower_bound_i(batch, nN, g);
      int hi = lower_bound_i(batch, nN, g + 1);
      s_inv[g] = 1.0f / fmaxf((float)(hi - lo), 1.0f);
    }
    __syncthreads();
    for (int idx = threadIdx.x; idx < nG * DIM; idx += 256) {
      out[idx] = outsum[idx] * s_inv[idx >> 7];
    }
  }
}

extern "C" void kernel_launch(void* const* d_in, const int* in_sizes, int n_in,
                              void* d_out, int out_size, void* d_ws, size_t ws_size,
                              hipStream_t stream) {
  const float* x     = (const float*)d_in[0];
  const int*   ei    = (const int*)d_in[1];
  const int*   batch = (const int*)d_in[2];
  const float* W_l   = (const float*)d_in[3];
  const float* b_l   = (const float*)d_in[4];
  const float* W_r   = (const float*)d_in[5];
  const float* gamma = (const float*)d_in[6];
  const float* beta  = (const float*)d_in[7];
  float* out = (float*)d_out;

  const int N = in_sizes[2];
  const int E = in_sizes[1] / 2;
  const int G = out_size / DIM;
  const int L = in_sizes[3] / (DIM * DIM);

  const int* src  = ei;
  const int* dstE = ei + E;

  const int nB = (N + SCAN_TILE - 1) / SCAN_TILE;

  // workspace layout (zeroed region contiguous: cnt|cursor|sums(L)|outsum|done)
  char* wsb = (char*)d_ws;
  unsigned short* h    = (unsigned short*)wsb; wsb += (size_t)N * DIM * sizeof(unsigned short);
  unsigned short* xh   = (unsigned short*)wsb; wsb += (size_t)N * DIM * sizeof(unsigned short);
  unsigned short* aggh = (unsigned short*)wsb; wsb += (size_t)N * DIM * sizeof(unsigned short);
  unsigned short* Wth  = (unsigned short*)wsb; wsb += (size_t)L * DIM * 256 * sizeof(unsigned short);
  unsigned short* Wtl  = (unsigned short*)wsb; wsb += (size_t)L * DIM * 256 * sizeof(unsigned short);
  char* zbase = wsb;
  int* cnt      = (int*)wsb;    wsb += (size_t)N * sizeof(int);
  int* cursor   = (int*)wsb;    wsb += (size_t)N * sizeof(int);
  float* sums   = (float*)wsb;  wsb += (size_t)L * 2 * DIM * sizeof(float);
  float* outsum = (float*)wsb;  wsb += (size_t)G * DIM * sizeof(float);
  int* done     = (int*)wsb;    wsb += 4 * sizeof(int);
  int zbytes = (int)((char*)wsb - zbase);
  int* rowptr = (int*)wsb;      wsb += (size_t)(N + 1) * sizeof(int);
  int* bsum   = (int*)wsb;      wsb += (size_t)nB * sizeof(int);
  int* eidx   = (int*)wsb;      wsb += (size_t)E * sizeof(int);

  // 1. zero region + W prep (one node)
  int n4 = zbytes / 16;
  int nW = L * DIM * 256;
  int prep_n = max(n4, nW);
  prep_kernel<<<(prep_n + 255) / 256, 256, 0, stream>>>((float4*)zbase, n4,
      W_l, W_r, Wth, Wtl, nW);
  // 2. histogram + bf16 shadow of x
  int total8 = N * (DIM / 8);
  int histcvt_n = max(E, total8);
  hist_cvt_kernel<<<(histcvt_n + 255) / 256, 256, 0, stream>>>(dstE, cnt, x, xh, E, total8);
  // 3-4. scan (scan2 folded into scan3)
  scan1_kernel<<<nB, 256, 0, stream>>>(cnt, bsum, N);
  scan3_kernel<<<nB, 256, 0, stream>>>(cnt, bsum, rowptr, nB, N);
  // 5. CSR fill
  fill_kernel<<<(E + 255) / 256, 256, 0, stream>>>(src, dstE, rowptr, cursor, eidx, E);

  for (int l = 0; l < L; ++l) {
    gather_kernel<<<(N * 16 + 255) / 256, 256, 0, stream>>>(xh, rowptr, eidx, aggh, N);
    gemm_mfma_kernel<<<(N + 127) / 128, 256, 0, stream>>>(aggh, xh,
        Wth + (size_t)l * DIM * 256, Wtl + (size_t)l * DIM * 256,
        b_l + (size_t)l * DIM, h, sums + (size_t)l * 2 * DIM, N);
    if (l < L - 1) {
      bn_relu_kernel<<<(N * (DIM / 8) + 255) / 256, 256, 0, stream>>>(
          h, sums + (size_t)l * 2 * DIM, gamma + (size_t)l * DIM,
          beta + (size_t)l * DIM, xh, N);
    } else {
      pool_fused_kernel<<<(N + POOL_ROWS - 1) / POOL_ROWS, 256, 0, stream>>>(
          h, sums + (size_t)l * 2 * DIM, gamma + (size_t)l * DIM,
          beta + (size_t)l * DIM, batch, outsum, out, done, N, G);
    }
  }
}

// Round 14
// 213.132 us; speedup vs baseline: 2.1605x; 1.4472x over previous
//
#include <hip/hip_runtime.h>

#define DIM 128
#define EPS 1e-5f
#define SCAN_TILE 2048  // 256 threads x 8 elements

typedef short s16x8 __attribute__((ext_vector_type(8)));
typedef unsigned short u16x8 __attribute__((ext_vector_type(8)));
typedef float f32x4 __attribute__((ext_vector_type(4)));

__device__ __forceinline__ int lower_bound_i(const int* __restrict__ a, int n, int key) {
  int lo = 0, hi = n;
  while (lo < hi) {
    int mid = (lo + hi) >> 1;
    if (a[mid] < key) lo = mid + 1; else hi = mid;
  }
  return lo;
}

__device__ __forceinline__ unsigned rne_bf16(float f) {
  unsigned u = __builtin_bit_cast(unsigned, f);
  return (u + 0x7fffu + ((u >> 16) & 1u)) >> 16;
}
__device__ __forceinline__ float bf16_hi_to_f32(unsigned h) {
  return __builtin_bit_cast(float, h << 16);
}

// --- prep: zero the zero-region AND split/transpose W (both layers) --------
__global__ __launch_bounds__(256) void prep_kernel(float4* __restrict__ z, int n4,
    const float* __restrict__ W_l, const float* __restrict__ W_r,
    unsigned short* __restrict__ Wth, unsigned short* __restrict__ Wtl, int nW) {
  int i = blockIdx.x * 256 + threadIdx.x;
  if (i < n4) z[i] = make_float4(0.f, 0.f, 0.f, 0.f);
  if (i < nW) {  // i = l*DIM*256 + c*256 + k
    int l = i / (DIM * 256);
    int rem = i - l * DIM * 256;
    int c = rem >> 8, k = rem & 255;
    const float* Wl = W_l + (size_t)l * DIM * DIM;
    const float* Wr = W_r + (size_t)l * DIM * DIM;
    float v = (k < DIM) ? Wl[(size_t)k * DIM + c] : Wr[(size_t)(k - DIM) * DIM + c];
    unsigned h = rne_bf16(v);
    float r = v - bf16_hi_to_f32(h);
    Wth[i] = (unsigned short)h;
    Wtl[i] = (unsigned short)rne_bf16(r);
  }
}

// --- histogram + bf16 shadow of layer-1 activations (merged) ---------------
__global__ __launch_bounds__(256) void hist_cvt_kernel(const int* __restrict__ dst,
    int* __restrict__ cnt, const float* __restrict__ x,
    unsigned short* __restrict__ xh, int nE, int total8) {
  int i = blockIdx.x * 256 + threadIdx.x;
  if (i < nE) atomicAdd(&cnt[dst[i]], 1);
  if (i < total8) {
    float4 a = reinterpret_cast<const float4*>(x)[i * 2];
    float4 b = reinterpret_cast<const float4*>(x)[i * 2 + 1];
    u16x8 o;
    o[0] = (unsigned short)rne_bf16(a.x); o[1] = (unsigned short)rne_bf16(a.y);
    o[2] = (unsigned short)rne_bf16(a.z); o[3] = (unsigned short)rne_bf16(a.w);
    o[4] = (unsigned short)rne_bf16(b.x); o[5] = (unsigned short)rne_bf16(b.y);
    o[6] = (unsigned short)rne_bf16(b.z); o[7] = (unsigned short)rne_bf16(b.w);
    reinterpret_cast<u16x8*>(xh)[i] = o;
  }
}

// --- 2-phase scan (scan2 folded into scan3) --------------------------------
__global__ __launch_bounds__(256) void scan1_kernel(const int* __restrict__ cnt,
                                                    int* __restrict__ bsum, int nN) {
  __shared__ int s[256];
  int t = threadIdx.x;
  int base = blockIdx.x * SCAN_TILE + t * 8;
  int sum = 0;
#pragma unroll
  for (int j = 0; j < 8; ++j) {
    int i = base + j;
    if (i < nN) sum += cnt[i];
  }
  s[t] = sum;
  __syncthreads();
  for (int off = 128; off > 0; off >>= 1) {
    if (t < off) s[t] += s[t + off];
    __syncthreads();
  }
  if (t == 0) bsum[blockIdx.x] = s[0];
}

// Each block locally prefix-scans the (small) bsum array, then does its tile.
__global__ __launch_bounds__(256) void scan3_kernel(const int* __restrict__ cnt,
                                                    const int* __restrict__ bsum,
                                                    int* __restrict__ rowptr,
                                                    int nB, int nN) {
  __shared__ int s[256];
  __shared__ int s_base;
  int t = threadIdx.x;
  if (t == 0) {
    int run = 0;
    for (int b = 0; b < nB; ++b) {
      if (b == blockIdx.x) { s_base = run; }
      run += bsum[b];
    }
    if (blockIdx.x == 0) rowptr[nN] = run;
  }
  int base = blockIdx.x * SCAN_TILE + t * 8;
  int v[8];
  int tsum = 0;
#pragma unroll
  for (int j = 0; j < 8; ++j) {
    int i = base + j;
    v[j] = (i < nN) ? cnt[i] : 0;
    tsum += v[j];
  }
  s[t] = tsum;
  __syncthreads();
  for (int off = 1; off < 256; off <<= 1) {
    int u = (t >= off) ? s[t - off] : 0;
    __syncthreads();
    s[t] += u;
    __syncthreads();
  }
  int run = s_base + ((t > 0) ? s[t - 1] : 0);
#pragma unroll
  for (int j = 0; j < 8; ++j) {
    int i = base + j;
    if (i < nN) rowptr[i] = run;
    run += v[j];
  }
}

__global__ __launch_bounds__(256) void fill_kernel(const int* __restrict__ src,
    const int* __restrict__ dst, const int* __restrict__ rowptr,
    int* __restrict__ cursor, int* __restrict__ eidx, int nE) {
  int e = blockIdx.x * 256 + threadIdx.x;
  if (e < nE) {
    int d = dst[e];
    int p = atomicAdd(&cursor[d], 1);
    eidx[rowptr[d] + p] = src[e];
  }
}

// --- mean-aggregate via gather: 16 threads per dst node, bf16 in/out -------
__global__ __launch_bounds__(256) void gather_kernel(const unsigned short* __restrict__ xh,
    const int* __restrict__ rowptr, const int* __restrict__ eidx,
    unsigned short* __restrict__ aggh, int nN) {
  int grp = (blockIdx.x * 256 + threadIdx.x) >> 4;
  int j = threadIdx.x & 15;  // 8 cols per lane
  if (grp >= nN) return;
  int lo = rowptr[grp], hi = rowptr[grp + 1];
  float acc[8] = {0.f, 0.f, 0.f, 0.f, 0.f, 0.f, 0.f, 0.f};
  int i = lo;
  for (; i + 1 < hi; i += 2) {
    int s0 = eidx[i], s1 = eidx[i + 1];
    u16x8 v0 = *reinterpret_cast<const u16x8*>(xh + (size_t)s0 * DIM + j * 8);
    u16x8 v1 = *reinterpret_cast<const u16x8*>(xh + (size_t)s1 * DIM + j * 8);
#pragma unroll
    for (int q = 0; q < 8; ++q) {
      acc[q] += bf16_hi_to_f32(v0[q]);
      acc[q] += bf16_hi_to_f32(v1[q]);
    }
  }
  if (i < hi) {
    int s0 = eidx[i];
    u16x8 v0 = *reinterpret_cast<const u16x8*>(xh + (size_t)s0 * DIM + j * 8);
#pragma unroll
    for (int q = 0; q < 8; ++q) acc[q] += bf16_hi_to_f32(v0[q]);
  }
  float invd = 1.0f / fmaxf((float)(hi - lo), 1.0f);
  u16x8 o;
#pragma unroll
  for (int q = 0; q < 8; ++q) o[q] = (unsigned short)rne_bf16(acc[q] * invd);
  *reinterpret_cast<u16x8*>(aggh + (size_t)grp * DIM + j * 8) = o;
}

// --- fused dual-GEMM (bf16 A x split-W MFMA) + BN-stats epilogue -----------
__global__ __launch_bounds__(256) void gemm_mfma_kernel(
    const unsigned short* __restrict__ A0h, const unsigned short* __restrict__ A1h,
    const unsigned short* __restrict__ Wth, const unsigned short* __restrict__ Wtl,
    const float* __restrict__ bias, unsigned short* __restrict__ h,
    float* __restrict__ sums, int nN) {
  __shared__ unsigned short Wh_lds[DIM * 128];  // 32KB, [c][k] swizzled
  __shared__ unsigned short Wl_lds[DIM * 128];  // 32KB
  __shared__ float s_sum[DIM];
  __shared__ float s_sq[DIM];
  const int tid = threadIdx.x;
  const int lane = tid & 63;
  const int wave = tid >> 6;
  const int rbase = blockIdx.x * 128 + wave * 32;
  const int lrow = lane & 15;
  const int koff = (lane >> 4) * 8;

  f32x4 acc[2][8];
#pragma unroll
  for (int rt = 0; rt < 2; ++rt)
#pragma unroll
    for (int ct = 0; ct < 8; ++ct)
      acc[rt][ct] = (f32x4){0.f, 0.f, 0.f, 0.f};

  int r0 = rbase + lrow;      if (r0 > nN - 1) r0 = nN - 1;
  int r1 = rbase + 16 + lrow; if (r1 > nN - 1) r1 = nN - 1;

#pragma unroll
  for (int s = 0; s < 2; ++s) {
    __syncthreads();
#pragma unroll
    for (int i = 0; i < 8; ++i) {
      int idx = i * 256 + tid;   // 0..2047
      int c = idx >> 4;
      int kc = idx & 15;
      int lb = c * 256 + ((kc * 16) ^ ((c & 7) << 4));
      float4 hv = *reinterpret_cast<const float4*>(Wth + (size_t)c * 256 + s * 128 + kc * 8);
      float4 lv = *reinterpret_cast<const float4*>(Wtl + (size_t)c * 256 + s * 128 + kc * 8);
      *reinterpret_cast<float4*>(reinterpret_cast<char*>(Wh_lds) + lb) = hv;
      *reinterpret_cast<float4*>(reinterpret_cast<char*>(Wl_lds) + lb) = lv;
    }
    __syncthreads();

    const unsigned short* A = s ? A1h : A0h;
#pragma unroll
    for (int ks = 0; ks < 4; ++ks) {
      int ka = ks * 32 + koff;
      s16x8 a0 = *reinterpret_cast<const s16x8*>(A + (size_t)r0 * DIM + ka);
      s16x8 a1 = *reinterpret_cast<const s16x8*>(A + (size_t)r1 * DIM + ka);
#pragma unroll
      for (int ct = 0; ct < 8; ++ct) {
        int c = ct * 16 + lrow;
        int lb = c * 256 + ((ka * 2) ^ ((c & 7) << 4));
        s16x8 wh = *reinterpret_cast<const s16x8*>(reinterpret_cast<const char*>(Wh_lds) + lb);
        s16x8 wl = *reinterpret_cast<const s16x8*>(reinterpret_cast<const char*>(Wl_lds) + lb);
        acc[0][ct] = __builtin_amdgcn_mfma_f32_16x16x32_bf16(a0, wh, acc[0][ct], 0, 0, 0);
        acc[0][ct] = __builtin_amdgcn_mfma_f32_16x16x32_bf16(a0, wl, acc[0][ct], 0, 0, 0);
        acc[1][ct] = __builtin_amdgcn_mfma_f32_16x16x32_bf16(a1, wh, acc[1][ct], 0, 0, 0);
        acc[1][ct] = __builtin_amdgcn_mfma_f32_16x16x32_bf16(a1, wl, acc[1][ct], 0, 0, 0);
      }
    }
  }

  // epilogue: store h (bf16) and accumulate BN stats from fp32 values
  if (tid < DIM) { s_sum[tid] = 0.f; s_sq[tid] = 0.f; }
  __syncthreads();
  float csum[8], csq[8];
#pragma unroll
  for (int ct = 0; ct < 8; ++ct) { csum[ct] = 0.f; csq[ct] = 0.f; }
#pragma unroll
  for (int ct = 0; ct < 8; ++ct) {
    int c = ct * 16 + lrow;
    float b = bias[c];
#pragma unroll
    for (int rt = 0; rt < 2; ++rt) {
      int rr = rbase + rt * 16 + (lane >> 4) * 4;
#pragma unroll
      for (int j = 0; j < 4; ++j) {
        int row = rr + j;
        if (row < nN) {
          float v = acc[rt][ct][j] + b;
          h[(size_t)row * DIM + c] = (unsigned short)rne_bf16(v);
          csum[ct] += v;
          csq[ct] += v * v;
        }
      }
    }
  }
#pragma unroll
  for (int ct = 0; ct < 8; ++ct) {
    csum[ct] += __shfl_xor(csum[ct], 16);
    csum[ct] += __shfl_xor(csum[ct], 32);
    csq[ct]  += __shfl_xor(csq[ct], 16);
    csq[ct]  += __shfl_xor(csq[ct], 32);
  }
  if (lane < 16) {
#pragma unroll
    for (int ct = 0; ct < 8; ++ct) {
      atomicAdd(&s_sum[ct * 16 + lane], csum[ct]);
      atomicAdd(&s_sq[ct * 16 + lane], csq[ct]);
    }
  }
  __syncthreads();
  if (tid < DIM) {
    atomicAdd(&sums[tid], s_sum[tid]);
    atomicAdd(&sums[DIM + tid], s_sq[tid]);
  }
}

// BN+ReLU: bf16 h in, bf16 activations out (8 elems/thread).
__global__ __launch_bounds__(256) void bn_relu_kernel(const unsigned short* __restrict__ h,
    const float* __restrict__ sums, const float* __restrict__ gamma,
    const float* __restrict__ beta, unsigned short* __restrict__ xhout, int nN) {
  int idx = blockIdx.x * 256 + threadIdx.x;
  int total = nN * (DIM / 8);
  if (idx >= total) return;
  int c = (idx & 15) * 8;
  float invN = 1.0f / (float)nN;
  u16x8 hv = reinterpret_cast<const u16x8*>(h)[idx];
  u16x8 oh;
#pragma unroll
  for (int j = 0; j < 8; ++j) {
    float mu = sums[c + j] * invN;
    float var = sums[DIM + c + j] * invN - mu * mu;
    float sc = gamma[c + j] * rsqrtf(var + EPS);
    float sh = beta[c + j] - mu * sc;
    float v = fmaxf(bf16_hi_to_f32(hv[j]) * sc + sh, 0.0f);
    oh[j] = (unsigned short)rne_bf16(v);
  }
  reinterpret_cast<u16x8*>(xhout)[idx] = oh;
}

// --- fused final BN+ReLU + segmented mean-pool (no cross-block sync) --------
#define POOL_ROWS 32
__global__ __launch_bounds__(256) void pool_fused_kernel(const unsigned short* __restrict__ h,
    const float* __restrict__ sums, const float* __restrict__ gamma,
    const float* __restrict__ beta, const int* __restrict__ batch,
    float* __restrict__ outsum, int nN) {
  int c = threadIdx.x & 127;
  int rp = threadIdx.x >> 7;
  int r0 = blockIdx.x * POOL_ROWS;
  float invN = 1.0f / (float)nN;
  float mu = sums[c] * invN;
  float var = sums[DIM + c] * invN - mu * mu;
  float sc = gamma[c] * rsqrtf(var + EPS);
  float sh = beta[c] - mu * sc;
  int rend = min(r0 + POOL_ROWS, nN);
  float acc = 0.f;
  int cur = -1;
  for (int r = r0 + rp; r < rend; r += 2) {
    int g = batch[r];
    float v = fmaxf(bf16_hi_to_f32(h[(size_t)r * DIM + c]) * sc + sh, 0.0f);
    if (g != cur) {
      if (cur >= 0) atomicAdd(&outsum[(size_t)cur * DIM + c], acc);
      cur = g; acc = 0.f;
    }
    acc += v;
  }
  if (cur >= 0) atomicAdd(&outsum[(size_t)cur * DIM + c], acc);
}

// One thread per output element; independent binary searches pipeline fine.
__global__ __launch_bounds__(256) void pool_div_kernel(const float* __restrict__ outsum,
    const int* __restrict__ batch, float* __restrict__ out, int nN, int nG) {
  int idx = blockIdx.x * 256 + threadIdx.x;  // g*128 + c
  if (idx >= nG * DIM) return;
  int g = idx >> 7;
  int lo = lower_bound_i(batch, nN, g);
  int hi = lower_bound_i(batch, nN, g + 1);
  float cnt = fmaxf((float)(hi - lo), 1.0f);
  out[idx] = outsum[idx] / cnt;
}

extern "C" void kernel_launch(void* const* d_in, const int* in_sizes, int n_in,
                              void* d_out, int out_size, void* d_ws, size_t ws_size,
                              hipStream_t stream) {
  const float* x     = (const float*)d_in[0];
  const int*   ei    = (const int*)d_in[1];
  const int*   batch = (const int*)d_in[2];
  const float* W_l   = (const float*)d_in[3];
  const float* b_l   = (const float*)d_in[4];
  const float* W_r   = (const float*)d_in[5];
  const float* gamma = (const float*)d_in[6];
  const float* beta  = (const float*)d_in[7];
  float* out = (float*)d_out;

  const int N = in_sizes[2];
  const int E = in_sizes[1] / 2;
  const int G = out_size / DIM;
  const int L = in_sizes[3] / (DIM * DIM);

  const int* src  = ei;
  const int* dstE = ei + E;

  const int nB = (N + SCAN_TILE - 1) / SCAN_TILE;

  // workspace layout (zeroed region contiguous: cnt|cursor|sums(L)|outsum)
  char* wsb = (char*)d_ws;
  unsigned short* h    = (unsigned short*)wsb; wsb += (size_t)N * DIM * sizeof(unsigned short);
  unsigned short* xh   = (unsigned short*)wsb; wsb += (size_t)N * DIM * sizeof(unsigned short);
  unsigned short* aggh = (unsigned short*)wsb; wsb += (size_t)N * DIM * sizeof(unsigned short);
  unsigned short* Wth  = (unsigned short*)wsb; wsb += (size_t)L * DIM * 256 * sizeof(unsigned short);
  unsigned short* Wtl  = (unsigned short*)wsb; wsb += (size_t)L * DIM * 256 * sizeof(unsigned short);
  char* zbase = wsb;
  int* cnt      = (int*)wsb;    wsb += (size_t)N * sizeof(int);
  int* cursor   = (int*)wsb;    wsb += (size_t)N * sizeof(int);
  float* sums   = (float*)wsb;  wsb += (size_t)L * 2 * DIM * sizeof(float);
  float* outsum = (float*)wsb;  wsb += (size_t)G * DIM * sizeof(float);
  int zbytes = (int)((char*)wsb - zbase);
  int* rowptr = (int*)wsb;      wsb += (size_t)(N + 1) * sizeof(int);
  int* bsum   = (int*)wsb;      wsb += (size_t)nB * sizeof(int);
  int* eidx   = (int*)wsb;      wsb += (size_t)E * sizeof(int);

  // 1. zero region + W prep (one node)
  int n4 = zbytes / 16;
  int nW = L * DIM * 256;
  int prep_n = max(n4, nW);
  prep_kernel<<<(prep_n + 255) / 256, 256, 0, stream>>>((float4*)zbase, n4,
      W_l, W_r, Wth, Wtl, nW);
  // 2. histogram + bf16 shadow of x
  int total8 = N * (DIM / 8);
  int histcvt_n = max(E, total8);
  hist_cvt_kernel<<<(histcvt_n + 255) / 256, 256, 0, stream>>>(dstE, cnt, x, xh, E, total8);
  // 3-4. scan (scan2 folded into scan3)
  scan1_kernel<<<nB, 256, 0, stream>>>(cnt, bsum, N);
  scan3_kernel<<<nB, 256, 0, stream>>>(cnt, bsum, rowptr, nB, N);
  // 5. CSR fill
  fill_kernel<<<(E + 255) / 256, 256, 0, stream>>>(src, dstE, rowptr, cursor, eidx, E);

  for (int l = 0; l < L; ++l) {
    gather_kernel<<<(N * 16 + 255) / 256, 256, 0, stream>>>(xh, rowptr, eidx, aggh, N);
    gemm_mfma_kernel<<<(N + 127) / 128, 256, 0, stream>>>(aggh, xh,
        Wth + (size_t)l * DIM * 256, Wtl + (size_t)l * DIM * 256,
        b_l + (size_t)l * DIM, h, sums + (size_t)l * 2 * DIM, N);
    if (l < L - 1) {
      bn_relu_kernel<<<(N * (DIM / 8) + 255) / 256, 256, 0, stream>>>(
          h, sums + (size_t)l * 2 * DIM, gamma + (size_t)l * DIM,
          beta + (size_t)l * DIM, xh, N);
    } else {
      pool_fused_kernel<<<(N + POOL_ROWS - 1) / POOL_ROWS, 256, 0, stream>>>(
          h, sums + (size_t)l * 2 * DIM, gamma + (size_t)l * DIM,
          beta + (size_t)l * DIM, batch, outsum, N);
      pool_div_kernel<<<(G * DIM + 255) / 256, 256, 0, stream>>>(outsum, batch, out, N, G);
    }
  }
}

// Round 15
// 205.611 us; speedup vs baseline: 2.2395x; 1.0366x over previous
//
#include <hip/hip_runtime.h>

#define DIM 128
#define EPS 1e-5f
#define SCAN_TILE 2048  // 256 threads x 8 elements

typedef short s16x8 __attribute__((ext_vector_type(8)));
typedef unsigned short u16x8 __attribute__((ext_vector_type(8)));
typedef float f32x4 __attribute__((ext_vector_type(4)));

__device__ __forceinline__ int lower_bound_i(const int* __restrict__ a, int n, int key) {
  int lo = 0, hi = n;
  while (lo < hi) {
    int mid = (lo + hi) >> 1;
    if (a[mid] < key) lo = mid + 1; else hi = mid;
  }
  return lo;
}

__device__ __forceinline__ unsigned rne_bf16(float f) {
  unsigned u = __builtin_bit_cast(unsigned, f);
  return (u + 0x7fffu + ((u >> 16) & 1u)) >> 16;
}
__device__ __forceinline__ float bf16_hi_to_f32(unsigned h) {
  return __builtin_bit_cast(float, h << 16);
}

// --- prep: zero the zero-region AND split/transpose W (both layers) --------
__global__ __launch_bounds__(256) void prep_kernel(float4* __restrict__ z, int n4,
    const float* __restrict__ W_l, const float* __restrict__ W_r,
    unsigned short* __restrict__ Wth, unsigned short* __restrict__ Wtl, int nW) {
  int i = blockIdx.x * 256 + threadIdx.x;
  if (i < n4) z[i] = make_float4(0.f, 0.f, 0.f, 0.f);
  if (i < nW) {  // i = l*DIM*256 + c*256 + k
    int l = i / (DIM * 256);
    int rem = i - l * DIM * 256;
    int c = rem >> 8, k = rem & 255;
    const float* Wl = W_l + (size_t)l * DIM * DIM;
    const float* Wr = W_r + (size_t)l * DIM * DIM;
    float v = (k < DIM) ? Wl[(size_t)k * DIM + c] : Wr[(size_t)(k - DIM) * DIM + c];
    unsigned h = rne_bf16(v);
    float r = v - bf16_hi_to_f32(h);
    Wth[i] = (unsigned short)h;
    Wtl[i] = (unsigned short)rne_bf16(r);
  }
}

// --- histogram + bf16 shadow of layer-1 activations (merged) ---------------
__global__ __launch_bounds__(256) void hist_cvt_kernel(const int* __restrict__ dst,
    int* __restrict__ cnt, const float* __restrict__ x,
    unsigned short* __restrict__ xh, int nE, int total8) {
  int i = blockIdx.x * 256 + threadIdx.x;
  if (i < nE) atomicAdd(&cnt[dst[i]], 1);
  if (i < total8) {
    float4 a = reinterpret_cast<const float4*>(x)[i * 2];
    float4 b = reinterpret_cast<const float4*>(x)[i * 2 + 1];
    u16x8 o;
    o[0] = (unsigned short)rne_bf16(a.x); o[1] = (unsigned short)rne_bf16(a.y);
    o[2] = (unsigned short)rne_bf16(a.z); o[3] = (unsigned short)rne_bf16(a.w);
    o[4] = (unsigned short)rne_bf16(b.x); o[5] = (unsigned short)rne_bf16(b.y);
    o[6] = (unsigned short)rne_bf16(b.z); o[7] = (unsigned short)rne_bf16(b.w);
    reinterpret_cast<u16x8*>(xh)[i] = o;
  }
}

// --- 2-phase scan (scan2 folded into scan3) --------------------------------
__global__ __launch_bounds__(256) void scan1_kernel(const int* __restrict__ cnt,
                                                    int* __restrict__ bsum, int nN) {
  __shared__ int s[256];
  int t = threadIdx.x;
  int base = blockIdx.x * SCAN_TILE + t * 8;
  int sum = 0;
#pragma unroll
  for (int j = 0; j < 8; ++j) {
    int i = base + j;
    if (i < nN) sum += cnt[i];
  }
  s[t] = sum;
  __syncthreads();
  for (int off = 128; off > 0; off >>= 1) {
    if (t < off) s[t] += s[t + off];
    __syncthreads();
  }
  if (t == 0) bsum[blockIdx.x] = s[0];
}

__global__ __launch_bounds__(256) void scan3_kernel(const int* __restrict__ cnt,
                                                    const int* __restrict__ bsum,
                                                    int* __restrict__ rowptr,
                                                    int nB, int nN) {
  __shared__ int s[256];
  __shared__ int s_base;
  int t = threadIdx.x;
  if (t == 0) {
    int run = 0;
    for (int b = 0; b < nB; ++b) {
      if (b == blockIdx.x) { s_base = run; }
      run += bsum[b];
    }
    if (blockIdx.x == 0) rowptr[nN] = run;
  }
  int base = blockIdx.x * SCAN_TILE + t * 8;
  int v[8];
  int tsum = 0;
#pragma unroll
  for (int j = 0; j < 8; ++j) {
    int i = base + j;
    v[j] = (i < nN) ? cnt[i] : 0;
    tsum += v[j];
  }
  s[t] = tsum;
  __syncthreads();
  for (int off = 1; off < 256; off <<= 1) {
    int u = (t >= off) ? s[t - off] : 0;
    __syncthreads();
    s[t] += u;
    __syncthreads();
  }
  int run = s_base + ((t > 0) ? s[t - 1] : 0);
#pragma unroll
  for (int j = 0; j < 8; ++j) {
    int i = base + j;
    if (i < nN) rowptr[i] = run;
    run += v[j];
  }
}

__global__ __launch_bounds__(256) void fill_kernel(const int* __restrict__ src,
    const int* __restrict__ dst, const int* __restrict__ rowptr,
    int* __restrict__ cursor, int* __restrict__ eidx, int nE) {
  int e = blockIdx.x * 256 + threadIdx.x;
  if (e < nE) {
    int d = dst[e];
    int p = atomicAdd(&cursor[d], 1);
    eidx[rowptr[d] + p] = src[e];
  }
}

// --- mean-aggregate gather with optional on-the-fly BN+ReLU ----------------
// bnsums==nullptr: read xin raw (layer 1). Else: v = max(v*sc+sh, 0) using
// layer-(l-1) batch stats (complete before this kernel launches).
__global__ __launch_bounds__(256) void gather_kernel(const unsigned short* __restrict__ xin,
    const int* __restrict__ rowptr, const int* __restrict__ eidx,
    unsigned short* __restrict__ aggh,
    const float* __restrict__ bnsums, const float* __restrict__ gamma,
    const float* __restrict__ beta, int nN) {
  int grp = (blockIdx.x * 256 + threadIdx.x) >> 4;
  int j = threadIdx.x & 15;  // 8 cols per lane
  if (grp >= nN) return;
  int lo = rowptr[grp], hi = rowptr[grp + 1];
  float acc[8] = {0.f, 0.f, 0.f, 0.f, 0.f, 0.f, 0.f, 0.f};
  int i = lo;
  if (bnsums) {
    float scv[8], shv[8];
    float invN = 1.0f / (float)nN;
#pragma unroll
    for (int q = 0; q < 8; ++q) {
      int c = j * 8 + q;
      float mu = bnsums[c] * invN;
      float var = bnsums[DIM + c] * invN - mu * mu;
      float sc = gamma[c] * rsqrtf(var + EPS);
      scv[q] = sc;
      shv[q] = beta[c] - mu * sc;
    }
    for (; i + 3 < hi; i += 4) {
      int s0 = eidx[i], s1 = eidx[i + 1], s2 = eidx[i + 2], s3 = eidx[i + 3];
      u16x8 v0 = *reinterpret_cast<const u16x8*>(xin + (size_t)s0 * DIM + j * 8);
      u16x8 v1 = *reinterpret_cast<const u16x8*>(xin + (size_t)s1 * DIM + j * 8);
      u16x8 v2 = *reinterpret_cast<const u16x8*>(xin + (size_t)s2 * DIM + j * 8);
      u16x8 v3 = *reinterpret_cast<const u16x8*>(xin + (size_t)s3 * DIM + j * 8);
#pragma unroll
      for (int q = 0; q < 8; ++q) {
        acc[q] += fmaxf(bf16_hi_to_f32(v0[q]) * scv[q] + shv[q], 0.f);
        acc[q] += fmaxf(bf16_hi_to_f32(v1[q]) * scv[q] + shv[q], 0.f);
        acc[q] += fmaxf(bf16_hi_to_f32(v2[q]) * scv[q] + shv[q], 0.f);
        acc[q] += fmaxf(bf16_hi_to_f32(v3[q]) * scv[q] + shv[q], 0.f);
      }
    }
    for (; i < hi; ++i) {
      int s0 = eidx[i];
      u16x8 v0 = *reinterpret_cast<const u16x8*>(xin + (size_t)s0 * DIM + j * 8);
#pragma unroll
      for (int q = 0; q < 8; ++q)
        acc[q] += fmaxf(bf16_hi_to_f32(v0[q]) * scv[q] + shv[q], 0.f);
    }
  } else {
    for (; i + 3 < hi; i += 4) {
      int s0 = eidx[i], s1 = eidx[i + 1], s2 = eidx[i + 2], s3 = eidx[i + 3];
      u16x8 v0 = *reinterpret_cast<const u16x8*>(xin + (size_t)s0 * DIM + j * 8);
      u16x8 v1 = *reinterpret_cast<const u16x8*>(xin + (size_t)s1 * DIM + j * 8);
      u16x8 v2 = *reinterpret_cast<const u16x8*>(xin + (size_t)s2 * DIM + j * 8);
      u16x8 v3 = *reinterpret_cast<const u16x8*>(xin + (size_t)s3 * DIM + j * 8);
#pragma unroll
      for (int q = 0; q < 8; ++q) {
        acc[q] += bf16_hi_to_f32(v0[q]) + bf16_hi_to_f32(v1[q]);
        acc[q] += bf16_hi_to_f32(v2[q]) + bf16_hi_to_f32(v3[q]);
      }
    }
    for (; i < hi; ++i) {
      int s0 = eidx[i];
      u16x8 v0 = *reinterpret_cast<const u16x8*>(xin + (size_t)s0 * DIM + j * 8);
#pragma unroll
      for (int q = 0; q < 8; ++q) acc[q] += bf16_hi_to_f32(v0[q]);
    }
  }
  float invd = 1.0f / fmaxf((float)(hi - lo), 1.0f);
  u16x8 o;
#pragma unroll
  for (int q = 0; q < 8; ++q) o[q] = (unsigned short)rne_bf16(acc[q] * invd);
  *reinterpret_cast<u16x8*>(aggh + (size_t)grp * DIM + j * 8) = o;
}

// --- fused dual-GEMM (bf16 A x split-W MFMA) + BN-stats epilogue -----------
// Root operand (s=1) read from `root` with optional on-the-fly BN+ReLU
// (bnsums != nullptr, layer-2: root == h, updated in place — each block reads
// only its own rows, and the epilogue barrier orders reads before writes).
__global__ __launch_bounds__(256) void gemm_mfma_kernel(
    const unsigned short* __restrict__ A0h, const unsigned short* __restrict__ root,
    const unsigned short* __restrict__ Wth, const unsigned short* __restrict__ Wtl,
    const float* __restrict__ bias, unsigned short* __restrict__ h,
    float* __restrict__ sums,
    const float* __restrict__ bnsums, const float* __restrict__ gamma,
    const float* __restrict__ beta, int nN) {
  __shared__ unsigned short Wh_lds[DIM * 128];  // 32KB, [c][k] swizzled
  __shared__ unsigned short Wl_lds[DIM * 128];  // 32KB
  __shared__ float s_sum[DIM];
  __shared__ float s_sq[DIM];
  __shared__ float s_sc[DIM];
  __shared__ float s_sh[DIM];
  const int tid = threadIdx.x;
  const int lane = tid & 63;
  const int wave = tid >> 6;
  const int rbase = blockIdx.x * 128 + wave * 32;
  const int lrow = lane & 15;
  const int koff = (lane >> 4) * 8;
  const bool bn = (bnsums != nullptr);

  if (bn && tid < DIM) {
    float invN = 1.0f / (float)nN;
    float mu = bnsums[tid] * invN;
    float var = bnsums[DIM + tid] * invN - mu * mu;
    float sc = gamma[tid] * rsqrtf(var + EPS);
    s_sc[tid] = sc;
    s_sh[tid] = beta[tid] - mu * sc;
  }

  f32x4 acc[2][8];
#pragma unroll
  for (int rt = 0; rt < 2; ++rt)
#pragma unroll
    for (int ct = 0; ct < 8; ++ct)
      acc[rt][ct] = (f32x4){0.f, 0.f, 0.f, 0.f};

  int r0 = rbase + lrow;      if (r0 > nN - 1) r0 = nN - 1;
  int r1 = rbase + 16 + lrow; if (r1 > nN - 1) r1 = nN - 1;

#pragma unroll
  for (int s = 0; s < 2; ++s) {
    __syncthreads();
#pragma unroll
    for (int i = 0; i < 8; ++i) {
      int idx = i * 256 + tid;   // 0..2047
      int c = idx >> 4;
      int kc = idx & 15;
      int lb = c * 256 + ((kc * 16) ^ ((c & 7) << 4));
      float4 hv = *reinterpret_cast<const float4*>(Wth + (size_t)c * 256 + s * 128 + kc * 8);
      float4 lv = *reinterpret_cast<const float4*>(Wtl + (size_t)c * 256 + s * 128 + kc * 8);
      *reinterpret_cast<float4*>(reinterpret_cast<char*>(Wh_lds) + lb) = hv;
      *reinterpret_cast<float4*>(reinterpret_cast<char*>(Wl_lds) + lb) = lv;
    }
    __syncthreads();

#pragma unroll
    for (int ks = 0; ks < 4; ++ks) {
      int ka = ks * 32 + koff;
      s16x8 a0, a1;
      if (s == 0) {
        a0 = *reinterpret_cast<const s16x8*>(A0h + (size_t)r0 * DIM + ka);
        a1 = *reinterpret_cast<const s16x8*>(A0h + (size_t)r1 * DIM + ka);
      } else if (!bn) {
        a0 = *reinterpret_cast<const s16x8*>(root + (size_t)r0 * DIM + ka);
        a1 = *reinterpret_cast<const s16x8*>(root + (size_t)r1 * DIM + ka);
      } else {
        u16x8 w0 = *reinterpret_cast<const u16x8*>(root + (size_t)r0 * DIM + ka);
        u16x8 w1 = *reinterpret_cast<const u16x8*>(root + (size_t)r1 * DIM + ka);
#pragma unroll
        for (int q = 0; q < 8; ++q) {
          float sc = s_sc[ka + q], sh = s_sh[ka + q];
          float f0 = fmaxf(bf16_hi_to_f32(w0[q]) * sc + sh, 0.f);
          float f1 = fmaxf(bf16_hi_to_f32(w1[q]) * sc + sh, 0.f);
          a0[q] = (short)rne_bf16(f0);
          a1[q] = (short)rne_bf16(f1);
        }
      }
#pragma unroll
      for (int ct = 0; ct < 8; ++ct) {
        int c = ct * 16 + lrow;
        int lb = c * 256 + ((ka * 2) ^ ((c & 7) << 4));
        s16x8 wh = *reinterpret_cast<const s16x8*>(reinterpret_cast<const char*>(Wh_lds) + lb);
        s16x8 wl = *reinterpret_cast<const s16x8*>(reinterpret_cast<const char*>(Wl_lds) + lb);
        acc[0][ct] = __builtin_amdgcn_mfma_f32_16x16x32_bf16(a0, wh, acc[0][ct], 0, 0, 0);
        acc[0][ct] = __builtin_amdgcn_mfma_f32_16x16x32_bf16(a0, wl, acc[0][ct], 0, 0, 0);
        acc[1][ct] = __builtin_amdgcn_mfma_f32_16x16x32_bf16(a1, wh, acc[1][ct], 0, 0, 0);
        acc[1][ct] = __builtin_amdgcn_mfma_f32_16x16x32_bf16(a1, wl, acc[1][ct], 0, 0, 0);
      }
    }
  }

  // epilogue: store h (bf16) and accumulate BN stats from fp32 values.
  // The barrier also orders all root-reads (above) before in-place h writes.
  if (tid < DIM) { s_sum[tid] = 0.f; s_sq[tid] = 0.f; }
  __syncthreads();
  float csum[8], csq[8];
#pragma unroll
  for (int ct = 0; ct < 8; ++ct) { csum[ct] = 0.f; csq[ct] = 0.f; }
#pragma unroll
  for (int ct = 0; ct < 8; ++ct) {
    int c = ct * 16 + lrow;
    float b = bias[c];
#pragma unroll
    for (int rt = 0; rt < 2; ++rt) {
      int rr = rbase + rt * 16 + (lane >> 4) * 4;
#pragma unroll
      for (int j = 0; j < 4; ++j) {
        int row = rr + j;
        if (row < nN) {
          float v = acc[rt][ct][j] + b;
          h[(size_t)row * DIM + c] = (unsigned short)rne_bf16(v);
          csum[ct] += v;
          csq[ct] += v * v;
        }
      }
    }
  }
#pragma unroll
  for (int ct = 0; ct < 8; ++ct) {
    csum[ct] += __shfl_xor(csum[ct], 16);
    csum[ct] += __shfl_xor(csum[ct], 32);
    csq[ct]  += __shfl_xor(csq[ct], 16);
    csq[ct]  += __shfl_xor(csq[ct], 32);
  }
  if (lane < 16) {
#pragma unroll
    for (int ct = 0; ct < 8; ++ct) {
      atomicAdd(&s_sum[ct * 16 + lane], csum[ct]);
      atomicAdd(&s_sq[ct * 16 + lane], csq[ct]);
    }
  }
  __syncthreads();
  if (tid < DIM) {
    atomicAdd(&sums[tid], s_sum[tid]);
    atomicAdd(&sums[DIM + tid], s_sq[tid]);
  }
}

// --- fused final BN+ReLU + segmented mean-pool (no cross-block sync) --------
#define POOL_ROWS 32
__global__ __launch_bounds__(256) void pool_fused_kernel(const unsigned short* __restrict__ h,
    const float* __restrict__ sums, const float* __restrict__ gamma,
    const float* __restrict__ beta, const int* __restrict__ batch,
    float* __restrict__ outsum, int nN) {
  int c = threadIdx.x & 127;
  int rp = threadIdx.x >> 7;
  int r0 = blockIdx.x * POOL_ROWS;
  float invN = 1.0f / (float)nN;
  float mu = sums[c] * invN;
  float var = sums[DIM + c] * invN - mu * mu;
  float sc = gamma[c] * rsqrtf(var + EPS);
  float sh = beta[c] - mu * sc;
  int rend = min(r0 + POOL_ROWS, nN);
  float acc = 0.f;
  int cur = -1;
  for (int r = r0 + rp; r < rend; r += 2) {
    int g = batch[r];
    float v = fmaxf(bf16_hi_to_f32(h[(size_t)r * DIM + c]) * sc + sh, 0.0f);
    if (g != cur) {
      if (cur >= 0) atomicAdd(&outsum[(size_t)cur * DIM + c], acc);
      cur = g; acc = 0.f;
    }
    acc += v;
  }
  if (cur >= 0) atomicAdd(&outsum[(size_t)cur * DIM + c], acc);
}

// One thread per output element; independent binary searches pipeline fine.
__global__ __launch_bounds__(256) void pool_div_kernel(const float* __restrict__ outsum,
    const int* __restrict__ batch, float* __restrict__ out, int nN, int nG) {
  int idx = blockIdx.x * 256 + threadIdx.x;  // g*128 + c
  if (idx >= nG * DIM) return;
  int g = idx >> 7;
  int lo = lower_bound_i(batch, nN, g);
  int hi = lower_bound_i(batch, nN, g + 1);
  float cnt = fmaxf((float)(hi - lo), 1.0f);
  out[idx] = outsum[idx] / cnt;
}

extern "C" void kernel_launch(void* const* d_in, const int* in_sizes, int n_in,
                              void* d_out, int out_size, void* d_ws, size_t ws_size,
                              hipStream_t stream) {
  const float* x     = (const float*)d_in[0];
  const int*   ei    = (const int*)d_in[1];
  const int*   batch = (const int*)d_in[2];
  const float* W_l   = (const float*)d_in[3];
  const float* b_l   = (const float*)d_in[4];
  const float* W_r   = (const float*)d_in[5];
  const float* gamma = (const float*)d_in[6];
  const float* beta  = (const float*)d_in[7];
  float* out = (float*)d_out;

  const int N = in_sizes[2];
  const int E = in_sizes[1] / 2;
  const int G = out_size / DIM;
  const int L = in_sizes[3] / (DIM * DIM);

  const int* src  = ei;
  const int* dstE = ei + E;

  const int nB = (N + SCAN_TILE - 1) / SCAN_TILE;

  // workspace layout (zeroed region contiguous: cnt|cursor|sums(L)|outsum)
  char* wsb = (char*)d_ws;
  unsigned short* h    = (unsigned short*)wsb; wsb += (size_t)N * DIM * sizeof(unsigned short);
  unsigned short* xh   = (unsigned short*)wsb; wsb += (size_t)N * DIM * sizeof(unsigned short);
  unsigned short* aggh = (unsigned short*)wsb; wsb += (size_t)N * DIM * sizeof(unsigned short);
  unsigned short* Wth  = (unsigned short*)wsb; wsb += (size_t)L * DIM * 256 * sizeof(unsigned short);
  unsigned short* Wtl  = (unsigned short*)wsb; wsb += (size_t)L * DIM * 256 * sizeof(unsigned short);
  char* zbase = wsb;
  int* cnt      = (int*)wsb;    wsb += (size_t)N * sizeof(int);
  int* cursor   = (int*)wsb;    wsb += (size_t)N * sizeof(int);
  float* sums   = (float*)wsb;  wsb += (size_t)L * 2 * DIM * sizeof(float);
  float* outsum = (float*)wsb;  wsb += (size_t)G * DIM * sizeof(float);
  int zbytes = (int)((char*)wsb - zbase);
  int* rowptr = (int*)wsb;      wsb += (size_t)(N + 1) * sizeof(int);
  int* bsum   = (int*)wsb;      wsb += (size_t)nB * sizeof(int);
  int* eidx   = (int*)wsb;      wsb += (size_t)E * sizeof(int);

  // 1. zero region + W prep (one node)
  int n4 = zbytes / 16;
  int nW = L * DIM * 256;
  int prep_n = max(n4, nW);
  prep_kernel<<<(prep_n + 255) / 256, 256, 0, stream>>>((float4*)zbase, n4,
      W_l, W_r, Wth, Wtl, nW);
  // 2. histogram + bf16 shadow of x
  int total8 = N * (DIM / 8);
  int histcvt_n = max(E, total8);
  hist_cvt_kernel<<<(histcvt_n + 255) / 256, 256, 0, stream>>>(dstE, cnt, x, xh, E, total8);
  // 3-4. scan
  scan1_kernel<<<nB, 256, 0, stream>>>(cnt, bsum, N);
  scan3_kernel<<<nB, 256, 0, stream>>>(cnt, bsum, rowptr, nB, N);
  // 5. CSR fill
  fill_kernel<<<(E + 255) / 256, 256, 0, stream>>>(src, dstE, rowptr, cursor, eidx, E);

  for (int l = 0; l < L; ++l) {
    const unsigned short* act = (l == 0) ? xh : h;
    const float* bnS = (l == 0) ? nullptr : sums + (size_t)(l - 1) * 2 * DIM;
    const float* gm  = gamma + (size_t)(l > 0 ? l - 1 : 0) * DIM;
    const float* bt  = beta + (size_t)(l > 0 ? l - 1 : 0) * DIM;
    gather_kernel<<<(N * 16 + 255) / 256, 256, 0, stream>>>(act, rowptr, eidx, aggh,
        bnS, gm, bt, N);
    gemm_mfma_kernel<<<(N + 127) / 128, 256, 0, stream>>>(aggh, act,
        Wth + (size_t)l * DIM * 256, Wtl + (size_t)l * DIM * 256,
        b_l + (size_t)l * DIM, h, sums + (size_t)l * 2 * DIM,
        bnS, gm, bt, N);
    if (l == L - 1) {
      pool_fused_kernel<<<(N + POOL_ROWS - 1) / POOL_ROWS, 256, 0, stream>>>(
          h, sums + (size_t)l * 2 * DIM, gamma + (size_t)l * DIM,
          beta + (size_t)l * DIM, batch, outsum, N);
      pool_div_kernel<<<(G * DIM + 255) / 256, 256, 0, stream>>>(outsum, batch, out, N, G);
    }
  }
}